// Round 5
// baseline (436.626 us; speedup 1.0000x reference)
//
#include <hip/hip_runtime.h>
#include <math.h>

// HydraAttention R5 — conv restructured: weights global->VGPR (L1-shared),
// halo-only LDS double-buffered with ONE barrier per channel chunk; GEMMs get
// the same dbuf single-barrier K-loop. normQ+denom fused.
//
// Pipeline:
//   prep1, prep_T, corr_k, transposeX
//   gemm_nt w1' = wr1 @ rwT           (rw folded into conv1 weights)
//   gemm_nt Qt  = xT @ qw^T + qb
//   gemm_nt KV  = [kw|vw] @ x + [kb|vb]
//   sumsqK -> scale_sums -> normQ_denom (fused L2-norm of Q + denom)
//   gemm_kv (split-n=8 f32 partials) -> reduce_kv
//   gemm_nt wv = (Qt @ kv + vsum)*den
//   conv3x3 mode0: h1T = conv(wvT, w1') + corr
//   conv3x3 mode1: out = (conv(h1T, wr2)+c2b)*x + x

typedef unsigned short u16;
typedef __attribute__((ext_vector_type(8))) short short8;
typedef __attribute__((ext_vector_type(4))) float f32x4;
typedef __attribute__((ext_vector_type(4))) unsigned short us4v;

#define ASYNC16(g, l) __builtin_amdgcn_global_load_lds( \
    (const __attribute__((address_space(1))) unsigned int*)(g), \
    (__attribute__((address_space(3))) unsigned int*)(l), 16, 0, 0)

static __device__ __forceinline__ float b2f(u16 h) {
  unsigned int u = ((unsigned int)h) << 16;
  return __builtin_bit_cast(float, u);
}
static __device__ __forceinline__ u16 f2b(float f) {
  unsigned int u = __builtin_bit_cast(unsigned int, f);
  u += 0x7fffu + ((u >> 16) & 1u);
  return (u16)(u >> 16);
}

#define NB 1048576L

// ---------------- prep1: weight converts/reorders + kvbias ----------------
__global__ __launch_bounds__(256) void prep1(
    const float* __restrict__ qw, const float* __restrict__ kw,
    const float* __restrict__ vw, const float* __restrict__ rw,
    const float* __restrict__ c1w, const float* __restrict__ c2w,
    const float* __restrict__ kb, const float* __restrict__ vb,
    u16* __restrict__ qw16, u16* __restrict__ kvw16, u16* __restrict__ rwT16,
    u16* __restrict__ wr1, u16* __restrict__ wr2,
    float* __restrict__ kvbias)
{
  if (blockIdx.x == 5632) {
    int t = threadIdx.x;
    if (t < 512) kvbias[t] = (t < 256) ? kb[t] : vb[t - 256];
    return;
  }
  long g = (long)blockIdx.x * 256 + threadIdx.x;
  if (g < 65536) {
    qw16[g] = f2b(qw[g]);
  } else if (g < 196608) {
    long e = g - 65536;
    kvw16[e] = f2b(e < 65536 ? kw[e] : vw[e - 65536]);
  } else if (g < 262144) {
    long e = g - 196608;
    int cv = e >> 8, co = e & 255;
    rwT16[e] = f2b(rw[co * 256 + cv]);
  } else if (g < 851968) {
    long e = g - 262144;
    int m = e / 2304, r = e - m * 2304;
    int d = r >> 8, c = r & 255;
    wr1[e] = f2b(c1w[m * 2304 + c * 9 + d]);
  } else {
    long e = g - 851968;
    int m = e / 2304, r = e - m * 2304;
    int d = r >> 8, c = r & 255;
    wr2[e] = f2b(c2w[m * 2304 + c * 9 + d]);
  }
}

// T[m*9+t] = sum_co c1w[m][co][t]*rb[co]
__global__ __launch_bounds__(256) void prep_T(
    const float* __restrict__ c1w, const float* __restrict__ rb, float* __restrict__ T)
{
  int e = blockIdx.x * 256 + threadIdx.x;   // 2304
  int m = e / 9, d = e - m * 9;
  float s = 0.f;
  for (int co = 0; co < 256; co++) s += c1w[m * 2304 + co * 9 + d] * rb[co];
  T[e] = s;
}

// corr[m][p] = c1b[m] + sum_{t valid at p} T[m][t]
__global__ __launch_bounds__(256) void corr_k(
    const float* __restrict__ T, const float* __restrict__ c1b, float* __restrict__ corr)
{
  int e = blockIdx.x * 256 + threadIdx.x;   // 1048576
  int m = e >> 12, p = e & 4095;
  int y = p >> 6, xx = p & 63;
  float s = c1b[m];
#pragma unroll
  for (int d = 0; d < 9; d++) {
    int dy = d / 3 - 1, dx = d - (d / 3) * 3 - 1;
    if ((unsigned)(y + dy) < 64u && (unsigned)(xx + dx) < 64u) s += T[m * 9 + d];
  }
  corr[e] = s;
}

// ---------------- x [b][c][n] f32 -> xT16 [b][n][c] bf16 ----------------
__global__ __launch_bounds__(256) void transposeX(
    const float* __restrict__ x, u16* __restrict__ xT)
{
  __shared__ float T[64][65];
  int n0 = blockIdx.x * 64, c0 = blockIdx.y * 64, b = blockIdx.z;
  int t = threadIdx.x;
#pragma unroll
  for (int i = 0; i < 4; i++) {
    int c = (t >> 4) + i * 16, nn = (t & 15) * 4;
    float4 v = *(const float4*)&x[(long)b * NB + (long)(c0 + c) * 4096 + n0 + nn];
    T[c][nn] = v.x; T[c][nn + 1] = v.y; T[c][nn + 2] = v.z; T[c][nn + 3] = v.w;
  }
  __syncthreads();
#pragma unroll
  for (int i = 0; i < 4; i++) {
    int n = (t >> 4) + i * 16, cc = (t & 15) * 4;
    us4v o;
#pragma unroll
    for (int e = 0; e < 4; e++) o[e] = f2b(T[cc + e][n]);
    *(us4v*)&xT[(long)b * NB + (long)(n0 + n) * 256 + c0 + cc] = o;
  }
}

// ---------------- generic NT bf16 MFMA GEMM, double-buffered ----------------
// D[i][j] = sum_k A[i][k]*B[j][k]
// mode 0: v += (p1?p1[row]:0) + (p2?p2[col]:0)
// mode 2: v = (v + p1[b*256+col]) * p2[b*4096+row]
__global__ __launch_bounds__(256) void gemm_nt(
    const u16* __restrict__ A, const u16* __restrict__ B, u16* __restrict__ out,
    int K, int lda, int ldb, long sAb, long sBb, long sOb, long sR, long sC,
    int mode, const float* __restrict__ p1, const float* __restrict__ p2)
{
  __shared__ __align__(16) u16 As[2][4096];
  __shared__ __align__(16) u16 Bs[2][4096];
  int b = blockIdx.z;
  long i0 = (long)blockIdx.y * 128;
  long j0 = (long)blockIdx.x * 128;
  const u16* Ab = A + b * sAb + i0 * lda;
  const u16* Bb = B + b * sBb + j0 * ldb;
  int t = threadIdx.x, wave = t >> 6, lane = t & 63;
  int wi = (wave >> 1) * 64, wj = (wave & 1) * 64;
  int li = lane & 15, quad = lane >> 4;
  f32x4 acc[4][4];
#pragma unroll
  for (int i = 0; i < 4; i++)
#pragma unroll
    for (int j = 0; j < 4; j++) acc[i][j] = (f32x4){0.f, 0.f, 0.f, 0.f};

  auto stage = [&](int bb, int k0) {
#pragma unroll
    for (int h = 0; h < 2; h++) {
      int chunk = wave * 128 + h * 64 + lane;
      int r = chunk >> 2, q = chunk & 3;
      ASYNC16(Ab + (long)r * lda + k0 + q * 8, &As[bb][(wave * 128 + h * 64) * 8]);
      ASYNC16(Bb + (long)r * ldb + k0 + q * 8, &Bs[bb][(wave * 128 + h * 64) * 8]);
    }
  };

  stage(0, 0);
  __syncthreads();
  int KT = K >> 5;
#pragma unroll 1
  for (int kt = 0; kt < KT; kt++) {
    if (kt + 1 < KT) stage((kt + 1) & 1, (kt + 1) << 5);
    int bb = kt & 1;
    short8 af[4], bf[4];
#pragma unroll
    for (int s = 0; s < 4; s++) af[s] = *(const short8*)&As[bb][(wi + s * 16 + li) * 32 + quad * 8];
#pragma unroll
    for (int s = 0; s < 4; s++) bf[s] = *(const short8*)&Bs[bb][(wj + s * 16 + li) * 32 + quad * 8];
#pragma unroll
    for (int si = 0; si < 4; si++)
#pragma unroll
      for (int sj = 0; sj < 4; sj++)
        acc[si][sj] = __builtin_amdgcn_mfma_f32_16x16x32_bf16(af[si], bf[sj], acc[si][sj], 0, 0, 0);
    __syncthreads();
  }

#pragma unroll
  for (int si = 0; si < 4; si++)
#pragma unroll
    for (int sj = 0; sj < 4; sj++) {
      long col = j0 + wj + sj * 16 + li;
#pragma unroll
      for (int r = 0; r < 4; r++) {
        long row = i0 + wi + si * 16 + quad * 4 + r;
        float v = acc[si][sj][r];
        if (mode == 0) {
          if (p1) v += p1[row];
          if (p2) v += p2[col];
        } else {
          v = (v + p1[b * 256 + col]) * p2[b * 4096 + row];
        }
        out[b * sOb + row * sR + col * sC] = f2b(v);
      }
    }
}

// ---------------- kv split-n GEMM, double-buffered: part[sp][b][cv][ck] f32 ----------------
__global__ __launch_bounds__(256) void gemm_kv(
    const u16* __restrict__ KV, float* __restrict__ part)
{
  __shared__ __align__(16) u16 As[2][4096];
  __shared__ __align__(16) u16 Bs[2][4096];
  int z = blockIdx.z;
  int b = z & 7, sp = z >> 3;
  long i0 = (long)blockIdx.y * 128;   // ck
  long j0 = (long)blockIdx.x * 128;   // cv
  const u16* Ab = KV + (long)b * 2 * NB + i0 * 4096;
  const u16* Bb = KV + (long)b * 2 * NB + NB + j0 * 4096;
  int t = threadIdx.x, wave = t >> 6, lane = t & 63;
  int wi = (wave >> 1) * 64, wj = (wave & 1) * 64;
  int li = lane & 15, quad = lane >> 4;
  f32x4 acc[4][4];
#pragma unroll
  for (int i = 0; i < 4; i++)
#pragma unroll
    for (int j = 0; j < 4; j++) acc[i][j] = (f32x4){0.f, 0.f, 0.f, 0.f};

  auto stage = [&](int bb, int k0) {
#pragma unroll
    for (int h = 0; h < 2; h++) {
      int chunk = wave * 128 + h * 64 + lane;
      int r = chunk >> 2, q = chunk & 3;
      ASYNC16(Ab + (long)r * 4096 + k0 + q * 8, &As[bb][(wave * 128 + h * 64) * 8]);
      ASYNC16(Bb + (long)r * 4096 + k0 + q * 8, &Bs[bb][(wave * 128 + h * 64) * 8]);
    }
  };

  int kbase = sp * 512;
  stage(0, kbase);
  __syncthreads();
#pragma unroll 1
  for (int kt = 0; kt < 16; kt++) {
    if (kt + 1 < 16) stage((kt + 1) & 1, kbase + ((kt + 1) << 5));
    int bb = kt & 1;
    short8 af[4], bf[4];
#pragma unroll
    for (int s = 0; s < 4; s++) af[s] = *(const short8*)&As[bb][(wi + s * 16 + li) * 32 + quad * 8];
#pragma unroll
    for (int s = 0; s < 4; s++) bf[s] = *(const short8*)&Bs[bb][(wj + s * 16 + li) * 32 + quad * 8];
#pragma unroll
    for (int si = 0; si < 4; si++)
#pragma unroll
      for (int sj = 0; sj < 4; sj++)
        acc[si][sj] = __builtin_amdgcn_mfma_f32_16x16x32_bf16(af[si], bf[sj], acc[si][sj], 0, 0, 0);
    __syncthreads();
  }

  float* outp = part + ((long)sp * 8 + b) * 65536;
#pragma unroll
  for (int si = 0; si < 4; si++)
#pragma unroll
    for (int sj = 0; sj < 4; sj++) {
      long col = j0 + wj + sj * 16 + li;   // cv
#pragma unroll
      for (int r = 0; r < 4; r++) {
        long row = i0 + wi + si * 16 + quad * 4 + r;  // ck
        outp[col * 256 + row] = acc[si][sj][r];
      }
    }
}

__global__ __launch_bounds__(256) void reduce_kv(
    const float* __restrict__ part, u16* __restrict__ kvT)
{
  int g = blockIdx.x * 256 + threadIdx.x;  // 524288
  float s = 0.f;
#pragma unroll
  for (int sp = 0; sp < 8; sp++) s += part[(long)sp * 524288 + g];
  kvT[g] = f2b(s);
}

// ---------------- fused: L2-normalize Qt rows + den[b][n] ----------------
__global__ __launch_bounds__(256) void normQ_denom(
    u16* __restrict__ Qt, const float* __restrict__ ksum, float* __restrict__ den)
{
  int row = blockIdx.x * 4 + (threadIdx.x >> 6);
  int lane = threadIdx.x & 63;
  int b = row >> 12;
  u16* p = Qt + (long)row * 256 + lane * 4;
  us4v v = *(const us4v*)p;
  float f0 = b2f(v[0]), f1 = b2f(v[1]), f2 = b2f(v[2]), f3 = b2f(v[3]);
  float ss = f0 * f0 + f1 * f1 + f2 * f2 + f3 * f3;
#pragma unroll
  for (int m = 32; m; m >>= 1) ss += __shfl_xor(ss, m, 64);
  float r = 1.0f / sqrtf(ss);
  float g0 = f0 * r, g1 = f1 * r, g2 = f2 * r, g3 = f3 * r;
  us4v o;
  o[0] = f2b(g0); o[1] = f2b(g1); o[2] = f2b(g2); o[3] = f2b(g3);
  *(us4v*)p = o;
  float4 ks = *(const float4*)&ksum[b * 256 + lane * 4];
  float s = g0 * ks.x + g1 * ks.y + g2 * ks.z + g3 * ks.w;
#pragma unroll
  for (int m = 32; m; m >>= 1) s += __shfl_xor(s, m, 64);
  if (lane == 0) den[row] = 1.0f / (4096.0f + s + 1e-6f);
}

// ---------------- K column sumsq -> rsqK[b][n] ----------------
__global__ __launch_bounds__(256) void sumsqK(
    const u16* __restrict__ KV, float* __restrict__ rsqK)
{
  __shared__ float red[8][132];
  int b = blockIdx.x >> 5, nc = blockIdx.x & 31;
  int n0 = nc * 128;
  int t = threadIdx.x;
  int nn = (t & 31) * 4, cg = t >> 5;
  const u16* base = KV + (long)b * 2 * NB;
  float s0 = 0.f, s1 = 0.f, s2 = 0.f, s3 = 0.f;
  for (int st = 0; st < 32; st++) {
    int c = cg + st * 8;
    us4v v = *(const us4v*)(base + (long)c * 4096 + n0 + nn);
    float a = b2f(v[0]), bb = b2f(v[1]), cc = b2f(v[2]), dd = b2f(v[3]);
    s0 = fmaf(a, a, s0); s1 = fmaf(bb, bb, s1);
    s2 = fmaf(cc, cc, s2); s3 = fmaf(dd, dd, s3);
  }
  red[cg][nn] = s0; red[cg][nn + 1] = s1; red[cg][nn + 2] = s2; red[cg][nn + 3] = s3;
  __syncthreads();
  if (t < 128) {
    float s = 0.f;
#pragma unroll
    for (int g = 0; g < 8; g++) s += red[g][t];
    rsqK[b * 4096 + n0 + t] = 1.0f / sqrtf(s);
  }
}

// ---------------- scale K rows by rsqK + ksum; V rows -> vsum ----------------
__global__ __launch_bounds__(256) void scale_sums(
    u16* __restrict__ KV, const float* __restrict__ rsqK,
    float* __restrict__ ksum, float* __restrict__ vsum)
{
  int z = blockIdx.x;
  int isV = z >> 11, rem = z & 2047, b = rem >> 8, c = rem & 255;
  u16* row = KV + (long)b * 2 * NB + (long)isV * NB + (long)c * 4096;
  const float* rq = rsqK + b * 4096;
  int t = threadIdx.x;
  float s = 0.f;
  short8 v0 = *(const short8*)&row[t * 16];
  short8 v1 = *(const short8*)&row[t * 16 + 8];
  if (!isV) {
    short8 o0, o1;
#pragma unroll
    for (int e = 0; e < 8; e++) {
      float a = b2f((u16)v0[e]) * rq[t * 16 + e];
      float bb = b2f((u16)v1[e]) * rq[t * 16 + 8 + e];
      s += a + bb;
      o0[e] = (short)f2b(a); o1[e] = (short)f2b(bb);
    }
    *(short8*)&row[t * 16] = o0;
    *(short8*)&row[t * 16 + 8] = o1;
  } else {
#pragma unroll
    for (int e = 0; e < 8; e++) s += b2f((u16)v0[e]) + b2f((u16)v1[e]);
  }
#pragma unroll
  for (int off = 32; off; off >>= 1) s += __shfl_down(s, off, 64);
  __shared__ float red[4];
  if ((t & 63) == 0) red[t >> 6] = s;
  __syncthreads();
  if (t == 0)
    (isV ? vsum : ksum)[b * 256 + c] = red[0] + red[1] + red[2] + red[3];
}

// ---------------- 3x3 conv: weights global->VGPR, halo LDS double-buffered ----------------
// Block: 64 m x 256 n (4 image rows), 4 waves each 64m x 64n, ONE barrier per c0.
// mode 0: out16[b][n][256] = acc + corr[m][n]
// mode 1: out32[b][m][4096] = (acc + bias[m])*x + x
__global__ __launch_bounds__(256) void conv3x3_mfma(
    const u16* __restrict__ inT, const u16* __restrict__ wr,
    const float* __restrict__ cb, const float* __restrict__ xres,
    u16* __restrict__ out16, float* __restrict__ out32, int mode)
{
  __shared__ __align__(16) u16 Hs[2][12672];    // 2 x 396 pos x 32 ch = 50.7 KB
  int b = blockIdx.z;
  int m0 = blockIdx.y * 64;
  int n0 = blockIdx.x * 256;
  int r0 = n0 >> 6;                             // image rows r0..r0+3
  int t = threadIdx.x, wave = t >> 6, lane = t & 63;
  int li = lane & 15, quad = lane >> 4;
  int wj = wave * 64;
  const u16* inb = inT + (long)b * NB;
  const u16* wrm = wr + (long)m0 * 2304;
  f32x4 acc[4][4];
#pragma unroll
  for (int i = 0; i < 4; i++)
#pragma unroll
    for (int j = 0; j < 4; j++) acc[i][j] = (f32x4){0.f, 0.f, 0.f, 0.f};

  auto stageH = [&](int bb, int c0) {
#pragma unroll
    for (int i = 0; i < 7; i++) {
      int chunk = i * 256 + t;
      if (chunk < 1584) {
        int pos = chunk >> 2, q = chunk & 3;
        int rr = pos / 66, xx = pos - rr * 66;
        int ri = r0 + rr - 1, xi = xx - 1;
        if ((unsigned)ri < 64u && (unsigned)xi < 64u) {
          ASYNC16(inb + (long)((ri << 6) + xi) * 256 + c0 + q * 8,
                  &Hs[bb][(i * 256 + wave * 64) * 8]);
        } else {
          *(float4*)&Hs[bb][chunk * 8] = (float4){0.f, 0.f, 0.f, 0.f};
        }
      }
    }
  };

  stageH(0, 0);
  __syncthreads();
#pragma unroll 1
  for (int ci = 0; ci < 8; ci++) {
    if (ci < 7) stageH((ci + 1) & 1, (ci + 1) * 32);
    int bb = ci & 1;
    const u16* wb = wrm + ci * 32 + quad * 8;
#pragma unroll
    for (int d = 0; d < 9; d++) {
      int dy = d / 3, dx = d - dy * 3;
      short8 af[4], bf[4];
#pragma unroll
      for (int s = 0; s < 4; s++)
        af[s] = *(const short8*)(wb + (long)(s * 16 + li) * 2304 + d * 256);
#pragma unroll
      for (int s = 0; s < 4; s++) {
        int pl = wj + s * 16 + li;
        int hp = ((pl >> 6) + dy) * 66 + (pl & 63) + dx;
        bf[s] = *(const short8*)&Hs[bb][hp * 32 + quad * 8];
      }
#pragma unroll
      for (int si = 0; si < 4; si++)
#pragma unroll
        for (int sj = 0; sj < 4; sj++)
          acc[si][sj] = __builtin_amdgcn_mfma_f32_16x16x32_bf16(af[si], bf[sj], acc[si][sj], 0, 0, 0);
    }
    __syncthreads();
  }

#pragma unroll
  for (int si = 0; si < 4; si++)
#pragma unroll
    for (int sj = 0; sj < 4; sj++) {
      int n = n0 + wj + sj * 16 + li;
      int mb = m0 + si * 16 + quad * 4;
      if (mode == 0) {
        us4v o;
#pragma unroll
        for (int r = 0; r < 4; r++)
          o[r] = f2b(acc[si][sj][r] + cb[(long)(mb + r) * 4096 + n]);
        *(us4v*)&out16[(long)b * NB + (long)n * 256 + mb] = o;
      } else {
#pragma unroll
        for (int r = 0; r < 4; r++) {
          long a = (long)b * NB + (long)(mb + r) * 4096 + n;
          float xv = xres[a];
          out32[a] = fmaf(acc[si][sj][r] + cb[mb + r], xv, xv);
        }
      }
    }
}

// ---------------- host ----------------
extern "C" void kernel_launch(void* const* d_in, const int* in_sizes, int n_in,
                              void* d_out, int out_size, void* d_ws, size_t ws_size,
                              hipStream_t stream)
{
  const float* x   = (const float*)d_in[0];
  const float* qw  = (const float*)d_in[1];
  const float* qb  = (const float*)d_in[2];
  const float* kw  = (const float*)d_in[3];
  const float* kb  = (const float*)d_in[4];
  const float* vw  = (const float*)d_in[5];
  const float* vb  = (const float*)d_in[6];
  const float* rw  = (const float*)d_in[7];
  const float* rb  = (const float*)d_in[8];
  const float* c1w = (const float*)d_in[9];
  const float* c1b = (const float*)d_in[10];
  const float* c2w = (const float*)d_in[11];
  const float* c2b = (const float*)d_in[12];

  // ws layout (u16 units)
  u16* U     = (u16*)d_ws;
  u16* xT16  = U;                     // later wvT16
  u16* Qt16  = U + 8388608;           // later h1T16
  u16* KV16  = U + 16777216;
  u16* wr2   = U + 33554432;
  u16* kvT16 = U + 34144256;
  float* Fws = (float*)(U + 34668544);
  float* ksum = Fws;
  float* vsum = Fws + 2048;

  // d_out scratch (dead before conv2 writes; conv2 reads nothing from d_out)
  char* ob = (char*)d_out;
  float* kvpart = (float*)(ob + 0);           // 16777216 B
  float* den    = (float*)(ob + 16777216);    // 131072
  float* rsqK   = (float*)(ob + 16908288);    // 131072
  float* corr   = (float*)(ob + 17039360);    // 4194304
  u16*   w1p16  = (u16*)(ob + 21233664);      // 1179648
  u16*   wr1    = (u16*)(ob + 22413312);      // 1179648
  float* T      = (float*)(ob + 23592960);    // 36864
  u16*   rwT16  = (u16*)(ob + 23629824);      // 131072
  u16*   qw16   = (u16*)(ob + 23760896);      // 131072
  u16*   kvw16  = (u16*)(ob + 23891968);      // 262144
  float* kvbias = (float*)(ob + 24154112);    // 2048
  float* outF   = (float*)d_out;

  u16* wvT16 = xT16;
  u16* h1T16 = Qt16;

  dim3 blk(256);

  prep1<<<5633, blk, 0, stream>>>(qw, kw, vw, rw, c1w, c2w, kb, vb,
                                  qw16, kvw16, rwT16, wr1, wr2, kvbias);
  prep_T<<<9, blk, 0, stream>>>(c1w, rb, T);
  corr_k<<<4096, blk, 0, stream>>>(T, c1b, corr);
  transposeX<<<dim3(64, 4, 8), blk, 0, stream>>>(x, xT16);

  // w1' = wr1 @ rwT : folds rw into conv1 weights
  gemm_nt<<<dim3(2, 18, 1), blk, 0, stream>>>(wr1, rwT16, w1p16,
      256, 256, 256, 0L, 0L, 0L, 256L, 1L, 0, nullptr, nullptr);
  // Qt[b][n][ck] = xT @ qw^T + qb
  gemm_nt<<<dim3(2, 32, 8), blk, 0, stream>>>(xT16, qw16, Qt16,
      256, 256, 256, NB, 0L, NB, 256L, 1L, 0, nullptr, qb);
  // KV[b][cq][n] = [kw|vw] @ x + [kb|vb]
  gemm_nt<<<dim3(32, 4, 8), blk, 0, stream>>>(kvw16, xT16, KV16,
      256, 256, 256, 0L, NB, 2 * NB, 4096L, 1L, 0, kvbias, nullptr);

  sumsqK<<<256, blk, 0, stream>>>(KV16, rsqK);
  scale_sums<<<4096, blk, 0, stream>>>(KV16, rsqK, ksum, vsum);
  normQ_denom<<<8192, blk, 0, stream>>>(Qt16, ksum, den);

  gemm_kv<<<dim3(2, 2, 64), blk, 0, stream>>>(KV16, kvpart);
  reduce_kv<<<2048, blk, 0, stream>>>(kvpart, kvT16);

  // wvT[b][n][cv] = (Qt @ kv + vsum)*den
  gemm_nt<<<dim3(2, 32, 8), blk, 0, stream>>>(Qt16, kvT16, wvT16,
      256, 256, 256, NB, 65536L, NB, 256L, 1L, 2, vsum, den);

  conv3x3_mfma<<<dim3(16, 4, 8), blk, 0, stream>>>(wvT16, w1p16, corr, nullptr,
                                                   h1T16, nullptr, 0);
  conv3x3_mfma<<<dim3(16, 4, 8), blk, 0, stream>>>(h1T16, wr2, c2b, x,
                                                   nullptr, outF, 1);
}